// Round 17
// baseline (64.596 us; speedup 1.0000x reference)
//
#include <hip/hip_runtime.h>
#include <hip/hip_bf16.h>
#include <math.h>

#define B_ROWS 16384
#define DIM 1024

typedef __attribute__((ext_vector_type(4))) float f32x4;

static __device__ __forceinline__ unsigned short f2bf(float f) {
    union { float f; unsigned u; } v; v.f = f;
    unsigned r = v.u + 0x7FFF + ((v.u >> 16) & 1);  // RNE
    return (unsigned short)(r >> 16);
}

// f32 -> fp8 e4m3fn scalar (cold path: weight conversion only)
static __device__ __forceinline__ unsigned f2fp8(float f) {
    union { float f; unsigned u; } v; v.f = f;
    const unsigned s = (v.u >> 24) & 0x80u;
    const float a = fabsf(f);
    if (a >= 448.f) return s | 0x7Eu;
    if (a < 0.015625f) {
        const int q = (int)rintf(a * 512.f);
        return s | (unsigned)q;
    }
    unsigned b = v.u & 0x7fffffffu;
    b += 0x000FFFFFu + ((b >> 20) & 1u);
    const int e = (int)(b >> 23) - 127;
    const unsigned m = (b >> 20) & 7u;
    return s | (unsigned)((e + 7) << 3) | m;
}

// NATIVE packed converts (hot paths)
static __device__ __forceinline__ unsigned cvt4_fp8(float a, float b, float c, float d) {
    unsigned u;
    asm volatile("v_cvt_pk_fp8_f32 %0, %1, %2\n\t"
                 "v_cvt_pk_fp8_f32 %0, %3, %4 op_sel:[0,0,1]"
                 : "=v"(u) : "v"(a), "v"(b), "v"(c), "v"(d));
    return u;
}
static __device__ __forceinline__ unsigned cvt2_fp8(float a, float b) {
    unsigned u = 0;
    asm volatile("v_cvt_pk_fp8_f32 %0, %1, %2" : "+v"(u) : "v"(a), "v"(b));
    return u;
}

// async global -> LDS, 16 bytes per lane; lds base wave-uniform
static __device__ __forceinline__ void gload16(const void* g, void* l) {
    __builtin_amdgcn_global_load_lds(
        (const __attribute__((address_space(1))) unsigned int*)g,
        (__attribute__((address_space(3))) unsigned int*)l, 16, 0, 0);
}

// ---------------------------------------------------------------------------
// xdots_prep (2225 blocks):
//  [0,128):   W1 -> W1q (512x1024 fp8 e4m3 N x K, x64 scale)
//  [128,176): W2 -> W2q (256x512 fp8 x64), W3 -> W3q (256x256 fp8 x64)
//  176:       czz[6] cross-net scalar constants (f32 exact)
//  [177,...): x rows — 7 P-tables staged in LDS ONCE per block (kills the 7x
//    constant-load amplification), then per row the 8 exact f32 reductions
//    zp = {x.P3_0,x.P2_0,x.P1_0, x.P3_1,x.P2_1,x.P1_1, x.Wl, sum(x)} and the
//    fp8 copy of x (native cvt).  4 waves x 2 rows = 8 rows/block.
// ---------------------------------------------------------------------------
__global__ __launch_bounds__(256, 5) void xdots_prep(
    const float* __restrict__ x,
    const float* __restrict__ W1, const float* __restrict__ W2,
    const float* __restrict__ W3,
    const float* __restrict__ cw, const float* __restrict__ cb,
    const float* __restrict__ Wl,
    unsigned char* __restrict__ W1q,
    unsigned char* __restrict__ W2q, unsigned char* __restrict__ W3q,
    float* __restrict__ czz,
    unsigned char* __restrict__ xq,
    float* __restrict__ zparts) {
    __shared__ __align__(16) char smem[7 * 4096];   // 28 KB (union)
    const int tid  = threadIdx.x;
    const int lane = tid & 63;
    const int w    = tid >> 6;
    const int blk  = blockIdx.x;

    if (blk < 176) {
        // ---- weight -> fp8 x64, transposed via LDS tile ----
        unsigned char* tilec = (unsigned char*)smem;   // [64][72]
        const float* src; unsigned char* dst;
        int kt, nt, Ksrc, Nsrc, ldDst;
        if (blk < 128)      { kt = blk & 15;         nt = blk >> 4;         src = W1; dst = W1q; Ksrc = 1024; Nsrc = 500; ldDst = 1024; }
        else if (blk < 160) { kt = (blk - 128) & 7;  nt = (blk - 128) >> 3; src = W2; dst = W2q; Ksrc = 500;  Nsrc = 200; ldDst = 512;  }
        else                { kt = (blk - 160) & 3;  nt = (blk - 160) >> 2; src = W3; dst = W3q; Ksrc = 200;  Nsrc = 200; ldDst = 256;  }
        const int k0 = kt << 6, n0 = nt << 6;
        {
            const int r = tid >> 2, c0 = (tid & 3) << 4;
            const int kk = k0 + r;
#pragma unroll
            for (int i = 0; i < 16; ++i) {
                const int nn = n0 + c0 + i;
                const float v = (kk < Ksrc && nn < Nsrc) ? src[(size_t)kk * Nsrc + nn] * 64.f : 0.f;
                tilec[r * 72 + c0 + i] = (unsigned char)f2fp8(v);
            }
        }
        __syncthreads();
        {
            const int n = tid >> 2, kc = (tid & 3) << 4;
            unsigned char* o = dst + (size_t)(n0 + n) * ldDst + k0 + kc;
#pragma unroll
            for (int i = 0; i < 16; ++i) o[i] = tilec[(kc + i) * 72 + n];
        }
        return;
    } else if (blk == 176) {
        float* red = (float*)(smem + 20480);           // [4][6]
        float c[6] = {0.f, 0.f, 0.f, 0.f, 0.f, 0.f};
#pragma unroll
        for (int q = 0; q < 4; ++q) {
            const int k = tid * 4 + q;
            const float wl = Wl[k];
            {
                const float w2 = cw[1024 + k], w3 = cw[2048 + k];
                const float b1 = cb[k], b2 = cb[1024 + k], b3 = cb[2048 + k];
                c[0] += w2 * w3 * b1 * wl;
                c[1] += w3 * b2 * wl;
                c[2] += b3 * wl;
            }
            {
                const float w2 = cw[4096 + k], w3 = cw[5120 + k];
                const float b1 = cb[3072 + k], b2 = cb[4096 + k], b3 = cb[5120 + k];
                c[3] += w2 * w3 * b1 * wl;
                c[4] += w3 * b2 * wl;
                c[5] += b3 * wl;
            }
        }
#pragma unroll
        for (int j = 0; j < 6; ++j)
#pragma unroll
            for (int m = 1; m < 64; m <<= 1) c[j] += __shfl_xor(c[j], m, 64);
        if (lane == 0)
#pragma unroll
            for (int j = 0; j < 6; ++j) red[w * 6 + j] = c[j];
        __syncthreads();
        if (tid < 6) czz[tid] = red[tid] + red[6 + tid] + red[12 + tid] + red[18 + tid];
        return;
    }

    // ---- x path ----
    float* tbl = (float*)smem;   // tbl[j*1024+k], j: 0 pa3 1 pa2 2 pa1 3 pb3 4 pb2 5 pb1 6 wl
    {
        const int k = tid * 4;
        const float4 wl4 = *(const float4*)(Wl + k);
        const float4 c0 = *(const float4*)(cw + k);
        const float4 c1 = *(const float4*)(cw + 1024 + k);
        const float4 c2 = *(const float4*)(cw + 2048 + k);
        const float4 c3 = *(const float4*)(cw + 3072 + k);
        const float4 c4 = *(const float4*)(cw + 4096 + k);
        const float4 c5 = *(const float4*)(cw + 5120 + k);
        float4 pa1, pa2, pa3, pb1, pb2, pb3;
        pa1.x = c2.x * wl4.x; pa1.y = c2.y * wl4.y; pa1.z = c2.z * wl4.z; pa1.w = c2.w * wl4.w;
        pa2.x = c1.x * pa1.x; pa2.y = c1.y * pa1.y; pa2.z = c1.z * pa1.z; pa2.w = c1.w * pa1.w;
        pa3.x = c0.x * pa2.x; pa3.y = c0.y * pa2.y; pa3.z = c0.z * pa2.z; pa3.w = c0.w * pa2.w;
        pb1.x = c5.x * wl4.x; pb1.y = c5.y * wl4.y; pb1.z = c5.z * wl4.z; pb1.w = c5.w * wl4.w;
        pb2.x = c4.x * pb1.x; pb2.y = c4.y * pb1.y; pb2.z = c4.z * pb1.z; pb2.w = c4.w * pb1.w;
        pb3.x = c3.x * pb2.x; pb3.y = c3.y * pb2.y; pb3.z = c3.z * pb2.z; pb3.w = c3.w * pb2.w;
        *(float4*)(tbl + k)        = pa3;
        *(float4*)(tbl + 1024 + k) = pa2;
        *(float4*)(tbl + 2048 + k) = pa1;
        *(float4*)(tbl + 3072 + k) = pb3;
        *(float4*)(tbl + 4096 + k) = pb2;
        *(float4*)(tbl + 5120 + k) = pb1;
        *(float4*)(tbl + 6144 + k) = wl4;
    }
    __syncthreads();

    const int row0 = (blk - 177) * 8 + (w << 1);
    float d[2][8];
#pragma unroll
    for (int r = 0; r < 2; ++r)
#pragma unroll
        for (int j = 0; j < 8; ++j) d[r][j] = 0.f;

#pragma unroll
    for (int c = 0; c < 4; ++c) {
        const int kb = c * 256 + lane * 4;
        const float4 xv0 = *(const float4*)(x + (size_t)row0 * DIM + kb);
        const float4 xv1 = *(const float4*)(x + (size_t)(row0 + 1) * DIM + kb);
        float4 t[7];
#pragma unroll
        for (int j = 0; j < 7; ++j) t[j] = *(const float4*)(tbl + j * 1024 + kb);

#pragma unroll
        for (int j = 0; j < 7; ++j) {
            d[0][j] = fmaf(xv0.x, t[j].x, d[0][j]);
            d[0][j] = fmaf(xv0.y, t[j].y, d[0][j]);
            d[0][j] = fmaf(xv0.z, t[j].z, d[0][j]);
            d[0][j] = fmaf(xv0.w, t[j].w, d[0][j]);
            d[1][j] = fmaf(xv1.x, t[j].x, d[1][j]);
            d[1][j] = fmaf(xv1.y, t[j].y, d[1][j]);
            d[1][j] = fmaf(xv1.z, t[j].z, d[1][j]);
            d[1][j] = fmaf(xv1.w, t[j].w, d[1][j]);
        }
        d[0][7] += xv0.x + xv0.y + xv0.z + xv0.w;
        d[1][7] += xv1.x + xv1.y + xv1.z + xv1.w;

        *(unsigned*)(xq + (size_t)row0 * DIM + kb)       = cvt4_fp8(xv0.x, xv0.y, xv0.z, xv0.w);
        *(unsigned*)(xq + (size_t)(row0 + 1) * DIM + kb) = cvt4_fp8(xv1.x, xv1.y, xv1.z, xv1.w);
    }

#pragma unroll
    for (int r = 0; r < 2; ++r)
#pragma unroll
        for (int j = 0; j < 8; ++j)
#pragma unroll
            for (int m = 1; m < 64; m <<= 1)
                d[r][j] += __shfl_xor(d[r][j], m, 64);

    if (lane == 0) {
#pragma unroll
        for (int r = 0; r < 2; ++r) {
            float4 za = {d[r][0], d[r][1], d[r][2], d[r][3]};
            float4 zb = {d[r][4], d[r][5], d[r][6], d[r][7]};
            *(float4*)(zparts + (size_t)(row0 + r) * 8)     = za;
            *(float4*)(zparts + (size_t)(row0 + r) * 8 + 4) = zb;
        }
    }
}

// ---------------------------------------------------------------------------
// stage_fp8 (4-wave): 128-row x 128-byte fp8 tile, chunk = slot ^ (row&7).
// ---------------------------------------------------------------------------
static __device__ __forceinline__ void stage_fp8(
    const unsigned char* __restrict__ src, int rowBase, int kt,
    unsigned char* lds, int w, int lane) {
    const int r8   = lane >> 3;
    const int slot = lane & 7;
#pragma unroll
    for (int q = 0; q < 4; ++q) {
        const int blk   = q * 4 + w;
        const int row   = blk * 8 + r8;
        const int chunk = slot ^ (row & 7);
        gload16(src + (size_t)(rowBase + row) * 1024 + kt * 128 + chunk * 16,
                lds + blk * 1024);
    }
}

// stage_fp8w8 (8-wave): ROWS x 128-byte fp8 tile, K = row stride in bytes.
template <int ROWS>
static __device__ __forceinline__ void stage_fp8w8(
    const unsigned char* __restrict__ src, int K, int rowBase, int kt,
    unsigned char* lds, int w, int lane) {
    const int r8   = lane >> 3;
    const int slot = lane & 7;
#pragma unroll
    for (int q = 0; q < ROWS / 64; ++q) {
        const int blk   = q * 8 + w;
        const int row   = blk * 8 + r8;
        const int chunk = slot ^ (row & 7);
        gload16(src + (size_t)(rowBase + row) * K + kt * 128 + chunk * 16,
                lds + blk * 1024);
    }
}

// ---------------------------------------------------------------------------
// gemm_fp8: d1q = fp8(relu((xq @ W1q^T) / 64 + b1)).  Tile 128x128, BK=128
// (nK=8), 4 waves.  Core validated R15/R16; epilogue now emits fp8.
// ---------------------------------------------------------------------------
__global__ __launch_bounds__(256) void gemm_fp8(
    const unsigned char* __restrict__ A,    // 16384 x 1024 fp8
    const unsigned char* __restrict__ Bq,   // 512 x 1024 fp8 (N x K), x64
    const float* __restrict__ bias,         // b1 (500)
    unsigned char* __restrict__ C) {        // 16384 x 512 fp8
    constexpr int nK = 8;
    __shared__ unsigned char As[2][128 * 128];
    __shared__ unsigned char Bs[2][128 * 128];

    const int tid  = threadIdx.x;
    const int lane = tid & 63;
    const int wid  = tid >> 6;
    const int wm   = wid >> 1;
    const int wn   = wid & 1;
    const int g    = lane >> 4;
    const int r16  = lane & 15;

    const int cpx = gridDim.x >> 3;
    const int swz = (blockIdx.x & 7) * cpx + (blockIdx.x >> 3);
    const int rowBase = (swz >> 2) << 7;
    const int colBase = (swz & 3) << 7;

    f32x4 acc[4][4];
#pragma unroll
    for (int m = 0; m < 4; ++m)
#pragma unroll
        for (int n = 0; n < 4; ++n)
            acc[m][n] = (f32x4){0.f, 0.f, 0.f, 0.f};

    stage_fp8(A, rowBase, 0, As[0], wid, lane);
    stage_fp8(Bq, colBase, 0, Bs[0], wid, lane);
    asm volatile("s_waitcnt vmcnt(0)" ::: "memory");
    __builtin_amdgcn_s_barrier();
    asm volatile("" ::: "memory");

    for (int kt = 0; kt < nK; ++kt) {
        const int buf = kt & 1;
        if (kt + 1 < nK) {
            stage_fp8(A, rowBase, kt + 1, As[buf ^ 1], wid, lane);
            stage_fp8(Bq, colBase, kt + 1, Bs[buf ^ 1], wid, lane);
        }
        asm volatile("" ::: "memory");

        const unsigned char* Ab = As[buf];
        const unsigned char* Bb = Bs[buf];
#pragma unroll
        for (int ks = 0; ks < 4; ++ks) {
            long af[4], bf[4];
#pragma unroll
            for (int m = 0; m < 4; ++m) {
                const int row = wm * 64 + m * 16 + r16;
                const int byte = row * 128 +
                    ((((ks << 1) | (g >> 1)) ^ (row & 7)) << 4) + ((g & 1) << 3);
                af[m] = *(const long*)(Ab + byte);
            }
#pragma unroll
            for (int n = 0; n < 4; ++n) {
                const int row = wn * 64 + n * 16 + r16;
                const int byte = row * 128 +
                    ((((ks << 1) | (g >> 1)) ^ (row & 7)) << 4) + ((g & 1) << 3);
                bf[n] = *(const long*)(Bb + byte);
            }
#pragma unroll
            for (int m = 0; m < 4; ++m)
#pragma unroll
                for (int n = 0; n < 4; ++n)
                    acc[m][n] = __builtin_amdgcn_mfma_f32_16x16x32_fp8_fp8(
                        af[m], bf[n], acc[m][n], 0, 0, 0);
        }

        asm volatile("s_waitcnt vmcnt(0)" ::: "memory");
        __builtin_amdgcn_s_barrier();
        asm volatile("" ::: "memory");
    }

    // ---- epilogue: 1/64 + bias + relu -> fp8 LDS bounce -> coalesced out ----
    unsigned char* Cb = As[0];   // 16 KB = 128x128 fp8
#pragma unroll
    for (int n = 0; n < 4; ++n) {
        const int lcol = wn * 64 + n * 16 + r16;
        const int col = colBase + lcol;
        const float bv = (col < 500) ? bias[col] : 0.f;
#pragma unroll
        for (int m = 0; m < 4; ++m) {
            const int lrow = wm * 64 + m * 16 + g * 4;
            float v0 = acc[m][n][0] * 0.015625f + bv; v0 = v0 > 0.f ? v0 : 0.f;
            float v1 = acc[m][n][1] * 0.015625f + bv; v1 = v1 > 0.f ? v1 : 0.f;
            float v2 = acc[m][n][2] * 0.015625f + bv; v2 = v2 > 0.f ? v2 : 0.f;
            float v3 = acc[m][n][3] * 0.015625f + bv; v3 = v3 > 0.f ? v3 : 0.f;
            const unsigned u01 = cvt2_fp8(v0, v1);
            const unsigned u23 = cvt2_fp8(v2, v3);
            Cb[(lrow + 0) * 128 + lcol] = (unsigned char)(u01 & 0xff);
            Cb[(lrow + 1) * 128 + lcol] = (unsigned char)((u01 >> 8) & 0xff);
            Cb[(lrow + 2) * 128 + lcol] = (unsigned char)(u23 & 0xff);
            Cb[(lrow + 3) * 128 + lcol] = (unsigned char)((u23 >> 8) & 0xff);
        }
    }
    __syncthreads();

    {   // 16 KB / 256 threads = 64 B each
        const int row  = tid >> 1;
        const int half = tid & 1;
        const uint4* s = (const uint4*)(Cb + row * 128 + half * 64);
        uint4* dd = (uint4*)(C + (size_t)(rowBase + row) * 512 + colBase + half * 64);
        dd[0] = s[0]; dd[1] = s[1]; dd[2] = s[2]; dd[3] = s[3];
    }
}

// ---------------------------------------------------------------------------
// tail_fp8 (8 waves / 512 threads): per 64-row block, ALL fp8 —
//   phase 1: P = fp8(relu(d1q[64x512] @ W2q^T / 64 + b2))  (64x256 in LDS)
//   phase 2: acc2 = P @ W3q^T
//   tail = relu(acc2/64 + b3) . Wl[1024:]
//   z_i = Horner(zparts, s) + czz_i + tail + bl; out = sigmoid(z_i)
// ---------------------------------------------------------------------------
__global__ __launch_bounds__(512) void tail_fp8(
    const unsigned char* __restrict__ d1q,   // 16384 x 512 fp8
    const unsigned char* __restrict__ W2q,   // 256 x 512 fp8 (N x K), x64
    const float* __restrict__ b2,
    const unsigned char* __restrict__ W3q,   // 256 x 256 fp8 (N x K), x64
    const float* __restrict__ b3,
    const float* __restrict__ Wl, const float* __restrict__ bl,
    const float* __restrict__ zparts, const float* __restrict__ czz,
    float* __restrict__ out) {
    __shared__ unsigned char As[2][64 * 128];    // 16 KB
    __shared__ unsigned char Bs[2][256 * 128];   // 64 KB
    __shared__ unsigned char P[64 * 256];        // 16 KB
    __shared__ float part[8][64];

    const int tid  = threadIdx.x;
    const int lane = tid & 63;
    const int wid  = tid >> 6;     // 0..7
    const int wm   = wid >> 2;     // 0..1 (32-row halves)
    const int wn   = wid & 3;      // 0..3 (64-col quarters)
    const int g    = lane >> 4;
    const int r16  = lane & 15;
    const int rowBase = blockIdx.x << 6;

    f32x4 acc[2][4];
#pragma unroll
    for (int m = 0; m < 2; ++m)
#pragma unroll
        for (int n = 0; n < 4; ++n)
            acc[m][n] = (f32x4){0.f, 0.f, 0.f, 0.f};

    // ---- phase 1: d1q(64x512) @ W2q(256x512), BK=128, 4 K-steps ----
    stage_fp8w8<64>(d1q, 512, rowBase, 0, As[0], wid, lane);
    stage_fp8w8<256>(W2q, 512, 0, 0, Bs[0], wid, lane);

    for (int kt = 0; kt < 4; ++kt) {
        const int buf = kt & 1;
        if (kt + 1 < 4) {
            stage_fp8w8<64>(d1q, 512, rowBase, kt + 1, As[buf ^ 1], wid, lane);
            stage_fp8w8<256>(W2q, 512, 0, kt + 1, Bs[buf ^ 1], wid, lane);
            asm volatile("s_waitcnt vmcnt(5)" ::: "memory");
        } else {
            asm volatile("s_waitcnt vmcnt(0)" ::: "memory");
        }
        __builtin_amdgcn_s_barrier();
        asm volatile("" ::: "memory");

        const unsigned char* Ab = As[buf];
        const unsigned char* Bb = Bs[buf];
#pragma unroll
        for (int ks = 0; ks < 4; ++ks) {
            long af[2], bf[4];
#pragma unroll
            for (int m = 0; m < 2; ++m) {
                const int row = wm * 32 + m * 16 + r16;
                const int byte = row * 128 +
                    ((((ks << 1) | (g >> 1)) ^ (row & 7)) << 4) + ((g & 1) << 3);
                af[m] = *(const long*)(Ab + byte);
            }
#pragma unroll
            for (int n = 0; n < 4; ++n) {
                const int row = wn * 64 + n * 16 + r16;
                const int byte = row * 128 +
                    ((((ks << 1) | (g >> 1)) ^ (row & 7)) << 4) + ((g & 1) << 3);
                bf[n] = *(const long*)(Bb + byte);
            }
#pragma unroll
            for (int m = 0; m < 2; ++m)
#pragma unroll
                for (int n = 0; n < 4; ++n)
                    acc[m][n] = __builtin_amdgcn_mfma_f32_16x16x32_fp8_fp8(
                        af[m], bf[n], acc[m][n], 0, 0, 0);
        }
        asm volatile("s_waitcnt lgkmcnt(0)" ::: "memory");
        __builtin_amdgcn_s_barrier();
        asm volatile("" ::: "memory");
    }

    // ---- phase-1 epilogue: 1/64 + b2 + relu -> P fp8 (chunk-swizzled) ----
#pragma unroll
    for (int n = 0; n < 4; ++n) {
        const int col = wn * 64 + n * 16 + r16;
        const float bv = (col < 200) ? b2[col] : 0.f;
#pragma unroll
        for (int m = 0; m < 2; ++m) {
            const int lrow = wm * 32 + m * 16 + g * 4;
            float v0 = acc[m][n][0] * 0.015625f + bv; v0 = v0 > 0.f ? v0 : 0.f;
            float v1 = acc[m][n][1] * 0.015625f + bv; v1 = v1 > 0.f ? v1 : 0.f;
            float v2 = acc[m][n][2] * 0.015625f + bv; v2 = v2 > 0.f ? v2 : 0.f;
            float v3 = acc[m][n][3] * 0.015625f + bv; v3 = v3 > 0.f ? v3 : 0.f;
            const unsigned u01 = cvt2_fp8(v0, v1);
            const unsigned u23 = cvt2_fp8(v2, v3);
            const int cpos = col >> 4, clo = col & 15;
#pragma unroll
            for (int r = 0; r < 4; ++r) {
                const int row = lrow + r;
                const unsigned byteV = (r < 2) ? ((r == 0) ? u01 : (u01 >> 8))
                                               : ((r == 2) ? u23 : (u23 >> 8));
                P[row * 256 + ((cpos ^ (row & 7)) << 4) + clo] = (unsigned char)(byteV & 0xff);
            }
        }
    }
    asm volatile("s_waitcnt lgkmcnt(0)" ::: "memory");

    // ---- phase 2: P(64x256) @ W3q(256x256), BK=128, 2 K-steps ----
    stage_fp8w8<256>(W3q, 256, 0, 0, Bs[0], wid, lane);

    f32x4 acc2[2][4];
#pragma unroll
    for (int m = 0; m < 2; ++m)
#pragma unroll
        for (int n = 0; n < 4; ++n)
            acc2[m][n] = (f32x4){0.f, 0.f, 0.f, 0.f};

    for (int kt = 0; kt < 2; ++kt) {
        const int buf = kt & 1;
        if (kt + 1 < 2) {
            stage_fp8w8<256>(W3q, 256, 0, kt + 1, Bs[buf ^ 1], wid, lane);
            asm volatile("s_waitcnt vmcnt(4)" ::: "memory");
        } else {
            asm volatile("s_waitcnt vmcnt(0)" ::: "memory");
        }
        __builtin_amdgcn_s_barrier();
        asm volatile("" ::: "memory");

        const unsigned char* Bb = Bs[buf];
#pragma unroll
        for (int ks = 0; ks < 4; ++ks) {
            long af[2], bf[4];
#pragma unroll
            for (int m = 0; m < 2; ++m) {
                const int row = wm * 32 + m * 16 + r16;
                const int byte = row * 256 +
                    (((kt * 8 + ((ks << 1) | (g >> 1))) ^ (row & 7)) << 4) + ((g & 1) << 3);
                af[m] = *(const long*)(P + byte);
            }
#pragma unroll
            for (int n = 0; n < 4; ++n) {
                const int row = wn * 64 + n * 16 + r16;
                const int byte = row * 128 +
                    ((((ks << 1) | (g >> 1)) ^ (row & 7)) << 4) + ((g & 1) << 3);
                bf[n] = *(const long*)(Bb + byte);
            }
#pragma unroll
            for (int m = 0; m < 2; ++m)
#pragma unroll
                for (int n = 0; n < 4; ++n)
                    acc2[m][n] = __builtin_amdgcn_mfma_f32_16x16x32_fp8_fp8(
                        af[m], bf[n], acc2[m][n], 0, 0, 0);
        }
        asm volatile("s_waitcnt lgkmcnt(0)" ::: "memory");
        __builtin_amdgcn_s_barrier();
        asm volatile("" ::: "memory");
    }

    // ---- tail dot ----
    float wlv[4], b3v[4];
#pragma unroll
    for (int n = 0; n < 4; ++n) {
        const int col = wn * 64 + n * 16 + r16;
        wlv[n] = (col < 200) ? Wl[1024 + col] : 0.f;
        b3v[n] = (col < 200) ? b3[col] : 0.f;
    }
#pragma unroll
    for (int m = 0; m < 2; ++m) {
#pragma unroll
        for (int r = 0; r < 4; ++r) {
            float s = 0.f;
#pragma unroll
            for (int n = 0; n < 4; ++n) {
                float v = acc2[m][n][r] * 0.015625f + b3v[n];
                v = v > 0.f ? v : 0.f;
                s += v * wlv[n];
            }
            s += __shfl_xor(s, 1, 64);
            s += __shfl_xor(s, 2, 64);
            s += __shfl_xor(s, 4, 64);
            s += __shfl_xor(s, 8, 64);
            if (r16 == 0) part[wid][wm * 32 + m * 16 + g * 4 + r] = s;
        }
    }
    __syncthreads();

    if (tid < 64) {
        const int row = rowBase + tid;
        const int wmr = (tid >> 5) << 2;
        const float t = part[wmr][tid] + part[wmr + 1][tid] +
                        part[wmr + 2][tid] + part[wmr + 3][tid];
        const float blv = bl[0];
        const float* zp = zparts + (size_t)row * 8;
        float4 zpa = *(const float4*)(zp);       // P3_0 P2_0 P1_0 P3_1
        float4 zpb = *(const float4*)(zp + 4);   // P2_1 P1_1 P0   s
        const float s = zpb.w;
        const float z0 = ((zpa.x * s + zpa.y + czz[0]) * s + zpa.z + czz[1]) * s
                         + zpb.z + czz[2] + t + blv;
        const float z1 = ((zpa.w * s + zpb.x + czz[3]) * s + zpb.y + czz[4]) * s
                         + zpb.z + czz[5] + t + blv;
        out[row]          = 1.f / (1.f + expf(-z0));
        out[B_ROWS + row] = 1.f / (1.f + expf(-z1));
    }
}

// ---------------------------------------------------------------------------
extern "C" void kernel_launch(void* const* d_in, const int* in_sizes, int n_in,
                              void* d_out, int out_size, void* d_ws, size_t ws_size,
                              hipStream_t stream) {
    const float* x  = (const float*)d_in[0];
    const float* W1 = (const float*)d_in[3];
    const float* b1 = (const float*)d_in[4];
    const float* W2 = (const float*)d_in[5];
    const float* b2 = (const float*)d_in[6];
    const float* W3 = (const float*)d_in[7];
    const float* b3 = (const float*)d_in[8];
    const float* Wl = (const float*)d_in[9];
    const float* bl = (const float*)d_in[10];
    const float* cw = (const float*)d_in[11];
    const float* cb = (const float*)d_in[12];
    float* out = (float*)d_out;

    unsigned char* d1q = (unsigned char*)d_ws;            // 16384 x 512 fp8
    unsigned char* xq  = d1q + (size_t)16384 * 512;       // 16384 x 1024 fp8
    unsigned char* W1q = xq + (size_t)16384 * 1024;       // 512 x 1024 fp8
    unsigned char* W2q = W1q + (size_t)512 * 1024;        // 256 x 512 fp8
    unsigned char* W3q = W2q + (size_t)256 * 512;         // 256 x 256 fp8
    float* zparts = (float*)(W3q + (size_t)256 * 256);    // 16384 x 8
    float* czz = zparts + (size_t)16384 * 8;              // 6

    // weights -> fp8(x64) + exact f32 cross dots + x -> fp8 (LDS P-tables)
    xdots_prep<<<177 + 2048, 256, 0, stream>>>(
        x, W1, W2, W3, cw, cb, Wl, W1q, W2q, W3q, czz, xq, zparts);

    // d1q = fp8(relu((xq @ W1q) / 64 + b1))
    gemm_fp8<<<512, 256, 0, stream>>>(xq, W1q, b1, d1q);

    // fp8 tail: d2/d3/tail/cross-combine/sigmoid
    tail_fp8<<<256, 512, 0, stream>>>(d1q, W2q, b2, W3q, b3, Wl, bl,
                                      zparts, czz, out);
}